// Round 1
// baseline (6123.785 us; speedup 1.0000x reference)
//
#include <hip/hip_runtime.h>
#include <cstdint>

// RNNLM: embed-gather(shift) -> [LSTM x2] -> logits GEMM.
// Strategy: bf16 MFMA for all GEMMs (tolerance is bf16-level), fp32 gate math.
// Recurrence: 32-WG persistent kernel, Wh' (gate-interleaved, transposed, bf16)
// resident in LDS, one flag-array barrier per timestep, h double-buffered in global.

typedef float    f32x4  __attribute__((ext_vector_type(4)));
typedef __bf16   bf16x8 __attribute__((ext_vector_type(8)));
typedef uint16_t u16;

constexpr int BB = 8, T = 512, D = 512, V = 32000;
constexpr int M4 = BB * T;   // 4096 rows (b*T+t)
constexpr int G  = 4 * D;    // 2048 gates

static __device__ __forceinline__ u16 f2bf(float f) {
  union { float f; uint32_t u; } v{f};
  uint32_t r = v.u + 0x7fffu + ((v.u >> 16) & 1u);   // RNE
  return (u16)(r >> 16);
}
static __device__ __forceinline__ float sigm(float x)  { return 1.f / (1.f + __expf(-x)); }
static __device__ __forceinline__ float tanhr(float x) { return 1.f - 2.f / (__expf(2.f * x) + 1.f); }

// ---------------- embed gather with ShiftRight, f32 -> bf16 ----------------
__global__ void embed_kernel(const int* __restrict__ tok, const float* __restrict__ emb,
                             u16* __restrict__ Xbf) {
  int m = blockIdx.x;                 // m = b*T + t
  int b = m >> 9, t = m & 511;
  int id = t ? tok[b * T + t - 1] : 0;    // shifted token (pad token = 0 -> embed row 0)
  const float* src = emb + (size_t)id * D;
  u16* dst = Xbf + (size_t)m * D;
  for (int d = threadIdx.x; d < D; d += 256) dst[d] = f2bf(src[d]);
}

// ------------- transpose f32[512][Cn] -> bf16[Cn][512], optional gate-interleave -------------
// PERM: output row q = 4*d + tau for input col n = tau*512 + d  (i,f,g,o interleaved per d)
template <bool PERM>
__global__ void transpose_cast(const float* __restrict__ src, u16* __restrict__ dst, int Cn) {
  __shared__ float tl[64][65];
  int n0 = blockIdx.x * 64, k0 = blockIdx.y * 64;
  int tx = threadIdx.x & 63, ty = threadIdx.x >> 6;
  for (int r = ty; r < 64; r += 4) tl[r][tx] = src[(size_t)(k0 + r) * Cn + n0 + tx];
  __syncthreads();
  for (int r = ty; r < 64; r += 4) {
    int n = n0 + r;
    int q = PERM ? ((n & (D - 1)) * 4 + (n >> 9)) : n;
    dst[(size_t)q * D + k0 + tx] = f2bf(tl[tx][r]);
  }
}

__global__ void bias_perm(const float* __restrict__ b, float* __restrict__ bp) {
  int q = blockIdx.x * 256 + threadIdx.x;
  if (q < G) bp[q] = b[(q & 3) * D + (q >> 2)];
}

// ---------------- m97-style bf16 GEMM: C[M,N] = A[M,K] @ BT[N,K]^T + bias ----------------
// 128x128 tile, K-step 32, global_load_lds width=16 staging, 16x16x32 bf16 MFMA.
__global__ __launch_bounds__(256) void gemm_bt(
    const u16* __restrict__ A, const u16* __restrict__ BT,
    const float* __restrict__ bias, float* __restrict__ C, int N, int K) {
  __shared__ u16 As[128 * 32], Bs[128 * 32];
  const int lane = threadIdx.x & 63, wave = threadIdx.x >> 6;
  const int m0 = blockIdx.y * 128, n0 = blockIdx.x * 128;
  const int wm = (wave >> 1) * 64, wn = (wave & 1) * 64;
  const int lr = lane >> 2, lc = (lane & 3) * 8;   // 4 lanes x 16B cover one 32-elem k-slice
  f32x4 acc[4][4] = {};
  for (int kk = 0; kk < K; kk += 32) {
#pragma unroll
    for (int i = 0; i < 2; ++i) {
      int row = wave * 32 + i * 16;    // wave-uniform LDS base; HW scatters lane*16B
      __builtin_amdgcn_global_load_lds(
          (const __attribute__((address_space(1))) uint32_t*)(A + (size_t)(m0 + row + lr) * K + kk + lc),
          (__attribute__((address_space(3))) uint32_t*)(As + row * 32), 16, 0, 0);
      __builtin_amdgcn_global_load_lds(
          (const __attribute__((address_space(1))) uint32_t*)(BT + (size_t)(n0 + row + lr) * K + kk + lc),
          (__attribute__((address_space(3))) uint32_t*)(Bs + row * 32), 16, 0, 0);
    }
    __syncthreads();   // drains vmcnt (global_load_lds) per barrier semantics
    bf16x8 af[4], bf[4];
#pragma unroll
    for (int i = 0; i < 4; ++i) {
      af[i] = *(const bf16x8*)(As + (wm + i * 16 + (lane & 15)) * 32 + (lane >> 4) * 8);
      bf[i] = *(const bf16x8*)(Bs + (wn + i * 16 + (lane & 15)) * 32 + (lane >> 4) * 8);
    }
#pragma unroll
    for (int mi = 0; mi < 4; ++mi)
#pragma unroll
      for (int ni = 0; ni < 4; ++ni)
        acc[mi][ni] = __builtin_amdgcn_mfma_f32_16x16x32_bf16(af[mi], bf[ni], acc[mi][ni], 0, 0, 0);
    __syncthreads();
  }
  const int cr = (lane >> 4) * 4, cc = lane & 15;   // C/D: col=lane&15, row=quad*4+reg (m89)
#pragma unroll
  for (int ni = 0; ni < 4; ++ni) {
    int col = n0 + wn + ni * 16 + cc;
    float bv = bias[col];
#pragma unroll
    for (int mi = 0; mi < 4; ++mi) {
      size_t base = (size_t)(m0 + wm + mi * 16 + cr) * N + col;
#pragma unroll
      for (int r = 0; r < 4; ++r) C[base + (size_t)r * N] = acc[mi][ni][r] + bv;
    }
  }
}

// ---------------- persistent LSTM scan: 32 WGs, one flag-barrier per timestep ----------------
// WhT: [2048][512] bf16, rows gate-interleaved (q=4d+tau). xw: [4096][2048] f32 (bias folded).
// Hstep: bf16 [2][16][512] zero-init (rows 8..15 stay 0 = M-padding). Hseq: bf16 [4096][512].
__global__ __launch_bounds__(256) void lstm_scan(
    const u16* __restrict__ WhT, const float* __restrict__ xw,
    u16* __restrict__ Hstep, u16* __restrict__ Hseq, int* __restrict__ flags) {
  __shared__ u16 Wlds[64 * 512];     // this WG's 64 gate-columns of Wh', 64 KB
  __shared__ float Cst[4][16][16];
  const int tid = threadIdx.x, lane = tid & 63, wave = tid >> 6, wg = blockIdx.x;
  {
    const uint4* s = (const uint4*)(WhT + (size_t)wg * 64 * 512);
    uint4* dsh = (uint4*)Wlds;
    for (int i = tid; i < 64 * 512 / 8; i += 256) dsh[i] = s[i];
  }
  __syncthreads();
  const int fr = lane & 15, quad = lane >> 4;
  const int colbase = wave * 16;                  // wave owns 16 interleaved cols = 4 d x {i,f,g,o}
  const bool gl = lane < 32;
  const int b = lane & 7, dl = (lane >> 3) & 3;   // gate lanes: (batch, local d)
  const int dglob = wg * 16 + wave * 4 + dl;
  const int q16 = wg * 64 + wave * 16;
  float c_state = 0.f;
  for (int t = 0; t < T; ++t) {
    const u16* hr = Hstep + (size_t)(t & 1) * (16 * 512);
    f32x4 acc0 = {}, acc1 = {};                   // two chains halve MFMA dep latency
#pragma unroll
    for (int kb = 0; kb < 16; kb += 2) {
      bf16x8 a0 = *(const bf16x8*)(hr + fr * 512 + kb * 32 + quad * 8);
      bf16x8 w0 = *(const bf16x8*)(Wlds + (colbase + fr) * 512 + kb * 32 + quad * 8);
      acc0 = __builtin_amdgcn_mfma_f32_16x16x32_bf16(a0, w0, acc0, 0, 0, 0);
      bf16x8 a1 = *(const bf16x8*)(hr + fr * 512 + (kb + 1) * 32 + quad * 8);
      bf16x8 w1 = *(const bf16x8*)(Wlds + (colbase + fr) * 512 + (kb + 1) * 32 + quad * 8);
      acc1 = __builtin_amdgcn_mfma_f32_16x16x32_bf16(a1, w1, acc1, 0, 0, 0);
    }
    f32x4 acc = acc0 + acc1;
#pragma unroll
    for (int r = 0; r < 4; ++r) Cst[wave][quad * 4 + r][fr] = acc[r];
    __syncthreads();
    if (gl) {
      const float4 x4 = *(const float4*)(xw + (size_t)(b * T + t) * G + q16 + dl * 4);
      float pi = Cst[wave][b][dl * 4 + 0] + x4.x;
      float pf = Cst[wave][b][dl * 4 + 1] + x4.y;
      float pg = Cst[wave][b][dl * 4 + 2] + x4.z;
      float po = Cst[wave][b][dl * 4 + 3] + x4.w;
      float ig = sigm(pi), fg = sigm(pf), gg = tanhr(pg), og = sigm(po);
      c_state = fg * c_state + ig * gg;
      float h = og * tanhr(c_state);
      u16 hb = f2bf(h);
      Hstep[(size_t)((t + 1) & 1) * (16 * 512) + b * 512 + dglob] = hb;
      Hseq[(size_t)(b * T + t) * 512 + dglob] = hb;
    }
    __syncthreads();   // all waves' stores drained to L2 (barrier implies vmcnt(0))
    // flag-array barrier: per-WG release store, 32-lane acquire poll. Max skew < 1 step,
    // so the double-buffered Hstep read/write sets never collide.
    if (wave == 0) {
      if (lane == 0)
        __hip_atomic_store(&flags[wg], t + 1, __ATOMIC_RELEASE, __HIP_MEMORY_SCOPE_AGENT);
      for (;;) {
        int v = (lane < 32) ? __hip_atomic_load(&flags[lane], __ATOMIC_ACQUIRE, __HIP_MEMORY_SCOPE_AGENT)
                            : t + 1;
        if (__all(v >= t + 1)) break;
        __builtin_amdgcn_s_sleep(1);
      }
    }
    __syncthreads();
  }
}

extern "C" void kernel_launch(void* const* d_in, const int* in_sizes, int n_in,
                              void* d_out, int out_size, void* d_ws, size_t ws_size,
                              hipStream_t stream) {
  (void)in_sizes; (void)n_in; (void)out_size; (void)ws_size;
  const int*   tokens = (const int*)d_in[0];
  const float* embed  = (const float*)d_in[1];
  const float* Wx0 = (const float*)d_in[2];
  const float* Wh0 = (const float*)d_in[3];
  const float* b0  = (const float*)d_in[4];
  const float* Wx1 = (const float*)d_in[5];
  const float* Wh1 = (const float*)d_in[6];
  const float* b1  = (const float*)d_in[7];
  const float* Wout = (const float*)d_in[8];
  const float* bout = (const float*)d_in[9];

  char* ws = (char*)d_ws;
  size_t off = 0;
  auto alloc = [&](size_t bytes) -> char* {
    char* p = ws + off; off += (bytes + 255) & ~(size_t)255; return p;
  };
  float* xw  = (float*)alloc((size_t)M4 * G * 4);  // 32 MB; WoutT aliases this after scans
  u16* WoutT = (u16*)xw;
  u16* Xbf   = (u16*)alloc((size_t)M4 * D * 2);
  u16* WxT0  = (u16*)alloc((size_t)G * D * 2);
  u16* WhT0  = (u16*)alloc((size_t)G * D * 2);
  u16* WxT1  = (u16*)alloc((size_t)G * D * 2);
  u16* WhT1  = (u16*)alloc((size_t)G * D * 2);
  u16* Hbf0  = (u16*)alloc((size_t)M4 * D * 2);
  u16* Hbf1  = (u16*)alloc((size_t)M4 * D * 2);
  float* b0p = (float*)alloc(G * 4);
  float* b1p = (float*)alloc(G * 4);
  char* zbase = ws + off;                           // zero-init region (harness poisons ws)
  u16* Hstep0 = (u16*)alloc(2 * 16 * 512 * 2);
  u16* Hstep1 = (u16*)alloc(2 * 16 * 512 * 2);
  int* flags0 = (int*)alloc(256);
  int* flags1 = (int*)alloc(256);
  size_t zbytes = (size_t)((ws + off) - zbase);
  hipMemsetAsync(zbase, 0, zbytes, stream);

  embed_kernel<<<M4, 256, 0, stream>>>(tokens, embed, Xbf);
  transpose_cast<true ><<<dim3(G / 64, 8), 256, 0, stream>>>(Wx0, WxT0, G);
  transpose_cast<true ><<<dim3(G / 64, 8), 256, 0, stream>>>(Wh0, WhT0, G);
  transpose_cast<true ><<<dim3(G / 64, 8), 256, 0, stream>>>(Wx1, WxT1, G);
  transpose_cast<true ><<<dim3(G / 64, 8), 256, 0, stream>>>(Wh1, WhT1, G);
  bias_perm<<<G / 256, 256, 0, stream>>>(b0, b0p);
  bias_perm<<<G / 256, 256, 0, stream>>>(b1, b1p);

  gemm_bt<<<dim3(G / 128, M4 / 128), 256, 0, stream>>>(Xbf, WxT0, b0p, xw, G, D);
  lstm_scan<<<32, 256, 0, stream>>>(WhT0, xw, Hstep0, Hbf0, flags0);
  gemm_bt<<<dim3(G / 128, M4 / 128), 256, 0, stream>>>(Hbf0, WxT1, b1p, xw, G, D);
  lstm_scan<<<32, 256, 0, stream>>>(WhT1, xw, Hstep1, Hbf1, flags1);
  transpose_cast<false><<<dim3(V / 64, 8), 256, 0, stream>>>(Wout, WoutT, V);
  gemm_bt<<<dim3(V / 128, M4 / 128), 256, 0, stream>>>(Hbf1, WoutT, bout, (float*)d_out, V, D);
}

// Round 2
// 5630.470 us; speedup vs baseline: 1.0876x; 1.0876x over previous
//
#include <hip/hip_runtime.h>
#include <cstdint>

// RNNLM: embed-gather(shift) -> [LSTM x2, pipelined] -> logits GEMM.
// bf16 MFMA everywhere, fp32 gate math. Both LSTM layers fused in ONE
// persistent kernel (64 WGs): L0 (WGs 0..31) and L1 (WGs 32..63) advance
// concurrently, L1 lagging L0 by ~1 step. Weights register-resident.
// One flag per WG (64-B padded), all-wave polling, one __syncthreads/step.

typedef float    f32x4  __attribute__((ext_vector_type(4)));
typedef __bf16   bf16x8 __attribute__((ext_vector_type(8)));
typedef uint16_t u16;

constexpr int BB = 8, T = 512, D = 512, V = 32000;
constexpr int M4 = BB * T;   // 4096 rows (b*T+t)
constexpr int G  = 4 * D;    // 2048 gates
constexpr int FS = 16;       // flag stride in ints (64 B padding)

static __device__ __forceinline__ u16 f2bf(float f) {
  union { float f; uint32_t u; } v{f};
  uint32_t r = v.u + 0x7fffu + ((v.u >> 16) & 1u);   // RNE
  return (u16)(r >> 16);
}
static __device__ __forceinline__ float sigm(float x)  { return 1.f / (1.f + __expf(-x)); }
static __device__ __forceinline__ float tanhr(float x) { return 1.f - 2.f / (__expf(2.f * x) + 1.f); }

// ---------------- embed gather with ShiftRight, f32 -> bf16 ----------------
__global__ void embed_kernel(const int* __restrict__ tok, const float* __restrict__ emb,
                             u16* __restrict__ Xbf) {
  int m = blockIdx.x;                 // m = b*T + t
  int b = m >> 9, t = m & 511;
  int id = t ? tok[b * T + t - 1] : 0;
  const float* src = emb + (size_t)id * D;
  u16* dst = Xbf + (size_t)m * D;
  for (int d = threadIdx.x; d < D; d += 256) dst[d] = f2bf(src[d]);
}

// ------------- transpose f32[512][Cn] -> bf16[Cn][512], optional gate-interleave -------------
template <bool PERM>
__global__ void transpose_cast(const float* __restrict__ src, u16* __restrict__ dst, int Cn) {
  __shared__ float tl[64][65];
  int n0 = blockIdx.x * 64, k0 = blockIdx.y * 64;
  int tx = threadIdx.x & 63, ty = threadIdx.x >> 6;
  for (int r = ty; r < 64; r += 4) tl[r][tx] = src[(size_t)(k0 + r) * Cn + n0 + tx];
  __syncthreads();
  for (int r = ty; r < 64; r += 4) {
    int n = n0 + r;
    int q = PERM ? ((n & (D - 1)) * 4 + (n >> 9)) : n;
    dst[(size_t)q * D + k0 + tx] = f2bf(tl[tx][r]);
  }
}

__global__ void bias_perm(const float* __restrict__ b, float* __restrict__ bp) {
  int q = blockIdx.x * 256 + threadIdx.x;
  if (q < G) bp[q] = b[(q & 3) * D + (q >> 2)];
}

// ---------------- m97-style bf16 GEMM: C[M,N] = A[M,K] @ BT[N,K]^T + bias ----------------
__global__ __launch_bounds__(256) void gemm_bt(
    const u16* __restrict__ A, const u16* __restrict__ BT,
    const float* __restrict__ bias, float* __restrict__ C, int N, int K) {
  __shared__ u16 As[128 * 32], Bs[128 * 32];
  const int lane = threadIdx.x & 63, wave = threadIdx.x >> 6;
  const int m0 = blockIdx.y * 128, n0 = blockIdx.x * 128;
  const int wm = (wave >> 1) * 64, wn = (wave & 1) * 64;
  const int lr = lane >> 2, lc = (lane & 3) * 8;
  f32x4 acc[4][4] = {};
  for (int kk = 0; kk < K; kk += 32) {
#pragma unroll
    for (int i = 0; i < 2; ++i) {
      int row = wave * 32 + i * 16;
      __builtin_amdgcn_global_load_lds(
          (const __attribute__((address_space(1))) uint32_t*)(A + (size_t)(m0 + row + lr) * K + kk + lc),
          (__attribute__((address_space(3))) uint32_t*)(As + row * 32), 16, 0, 0);
      __builtin_amdgcn_global_load_lds(
          (const __attribute__((address_space(1))) uint32_t*)(BT + (size_t)(n0 + row + lr) * K + kk + lc),
          (__attribute__((address_space(3))) uint32_t*)(Bs + row * 32), 16, 0, 0);
    }
    __syncthreads();
    bf16x8 af[4], bf[4];
#pragma unroll
    for (int i = 0; i < 4; ++i) {
      af[i] = *(const bf16x8*)(As + (wm + i * 16 + (lane & 15)) * 32 + (lane >> 4) * 8);
      bf[i] = *(const bf16x8*)(Bs + (wn + i * 16 + (lane & 15)) * 32 + (lane >> 4) * 8);
    }
#pragma unroll
    for (int mi = 0; mi < 4; ++mi)
#pragma unroll
      for (int ni = 0; ni < 4; ++ni)
        acc[mi][ni] = __builtin_amdgcn_mfma_f32_16x16x32_bf16(af[mi], bf[ni], acc[mi][ni], 0, 0, 0);
    __syncthreads();
  }
  const int cr = (lane >> 4) * 4, cc = lane & 15;
#pragma unroll
  for (int ni = 0; ni < 4; ++ni) {
    int col = n0 + wn + ni * 16 + cc;
    float bv = bias[col];
#pragma unroll
    for (int mi = 0; mi < 4; ++mi) {
      size_t base = (size_t)(m0 + wm + mi * 16 + cr) * N + col;
#pragma unroll
      for (int r = 0; r < 4; ++r) C[base + (size_t)r * N] = acc[mi][ni][r] + bv;
    }
  }
}

// ---------------- fused 2-layer pipelined LSTM scan ----------------
// WGs 0..31: layer 0 (gates from register Wh0-frags + precomputed xw0).
// WGs 32..63: layer 1 (gates from register Wh1-frags on h1[t-1] + Wx1-frags on h0[t] + bias).
// Rings: H0ring/H1ring bf16 [2][16][512] (rows 8..15 zero-padding). flags[64] (64-B stride).
// Thresholds: L0 @step t: L0 flags>=t, L1 flags>=t-1 (ring anti-overrun).
//             L1 @step t: L0 flags>=t+1 (h0[t] ready), L1 flags>=t.
__global__ __launch_bounds__(256, 1) void lstm_fused(
    const u16* __restrict__ WhT0, const u16* __restrict__ WhT1, const u16* __restrict__ WxT1,
    const float* __restrict__ xw0, const float* __restrict__ b1p,
    u16* __restrict__ H0ring, u16* __restrict__ H1ring, u16* __restrict__ Hseq1,
    int* __restrict__ flags) {
  __shared__ float Cst[4][16][16];     // per-wave slice: C^T scratch (intra-wave only)
  const int tid = threadIdx.x, lane = tid & 63, wave = tid >> 6, wg = blockIdx.x;
  const bool L1 = wg >= 32;
  const int wgl = L1 ? wg - 32 : wg;
  const int q16 = wgl * 64 + wave * 16;      // this wave's 16 gate columns (q = 4d+tau)
  const int fr = lane & 15, quad = lane >> 4;
  const bool gl = lane < 32;
  const int b = lane & 7, dl = (lane >> 3) & 3;
  const int dbase = wgl * 16 + wave * 4;     // wave's 4 d-dims

  if (!L1) {
    // ---- layer 0 ----
    bf16x8 whf[16];
#pragma unroll
    for (int kb = 0; kb < 16; ++kb)
      whf[kb] = *(const bf16x8*)(WhT0 + (size_t)(q16 + fr) * 512 + kb * 32 + quad * 8);
    float c_state = 0.f;
    for (int t = 0; t < T; ++t) {
      const int thr = t - ((lane >= 32) ? 1 : 0);
      for (;;) {
        int v = __hip_atomic_load(&flags[lane * FS], __ATOMIC_ACQUIRE, __HIP_MEMORY_SCOPE_AGENT);
        if (__all(v >= thr)) break;
        __builtin_amdgcn_s_sleep(1);
      }
      float4 x4 = *(const float4*)(xw0 + (size_t)(b * T + t) * G + q16 + dl * 4);
      const u16* hA = H0ring + ((t & 1) ^ 1) * 8192;   // h0[t-1]
      f32x4 acc0 = {}, acc1 = {};
#pragma unroll
      for (int kb = 0; kb < 16; kb += 2) {
        bf16x8 a0 = *(const bf16x8*)(hA + fr * 512 + kb * 32 + quad * 8);
        acc0 = __builtin_amdgcn_mfma_f32_16x16x32_bf16(a0, whf[kb], acc0, 0, 0, 0);
        bf16x8 a1 = *(const bf16x8*)(hA + fr * 512 + (kb + 1) * 32 + quad * 8);
        acc1 = __builtin_amdgcn_mfma_f32_16x16x32_bf16(a1, whf[kb + 1], acc1, 0, 0, 0);
      }
      f32x4 acc = acc0 + acc1;
#pragma unroll
      for (int r = 0; r < 4; ++r) Cst[wave][quad * 4 + r][fr] = acc[r];
      int hv = 0;
      if (gl) {
        float pi = Cst[wave][b][dl * 4 + 0] + x4.x;
        float pf = Cst[wave][b][dl * 4 + 1] + x4.y;
        float pg = Cst[wave][b][dl * 4 + 2] + x4.z;
        float po = Cst[wave][b][dl * 4 + 3] + x4.w;
        float ig = sigm(pi), fg = sigm(pf), gg = tanhr(pg), og = sigm(po);
        c_state = fg * c_state + ig * gg;
        hv = f2bf(og * tanhr(c_state));
        int g0 = __shfl(hv, b + 0), g1 = __shfl(hv, b + 8);
        int g2 = __shfl(hv, b + 16), g3 = __shfl(hv, b + 24);
        if (lane < 8) {
          ushort4 p = { (u16)g0, (u16)g1, (u16)g2, (u16)g3 };
          *(ushort4*)(H0ring + (t & 1) * 8192 + b * 512 + dbase) = p;
        }
      }
      __syncthreads();   // per-wave vmcnt(0): all 4 waves' h-stores drained
      if (tid == 0)
        __hip_atomic_store(&flags[wg * FS], t + 1, __ATOMIC_RELEASE, __HIP_MEMORY_SCOPE_AGENT);
    }
  } else {
    // ---- layer 1 ----
    bf16x8 whf[16], wxf[16];
#pragma unroll
    for (int kb = 0; kb < 16; ++kb) {
      whf[kb] = *(const bf16x8*)(WhT1 + (size_t)(q16 + fr) * 512 + kb * 32 + quad * 8);
      wxf[kb] = *(const bf16x8*)(WxT1 + (size_t)(q16 + fr) * 512 + kb * 32 + quad * 8);
    }
    float4 bias4 = *(const float4*)(b1p + q16 + dl * 4);
    float c_state = 0.f;
    for (int t = 0; t < T; ++t) {
      const int thr = t + 1 - ((lane >= 32) ? 1 : 0);
      for (;;) {
        int v = __hip_atomic_load(&flags[lane * FS], __ATOMIC_ACQUIRE, __HIP_MEMORY_SCOPE_AGENT);
        if (__all(v >= thr)) break;
        __builtin_amdgcn_s_sleep(1);
      }
      const u16* hA0 = H0ring + (t & 1) * 8192;          // h0[t]
      const u16* hA1 = H1ring + ((t & 1) ^ 1) * 8192;    // h1[t-1]
      f32x4 acc0 = {}, acc1 = {}, acc2 = {}, acc3 = {};
#pragma unroll
      for (int kb = 0; kb < 16; kb += 2) {
        bf16x8 a0 = *(const bf16x8*)(hA0 + fr * 512 + kb * 32 + quad * 8);
        acc0 = __builtin_amdgcn_mfma_f32_16x16x32_bf16(a0, wxf[kb], acc0, 0, 0, 0);
        bf16x8 a1 = *(const bf16x8*)(hA1 + fr * 512 + kb * 32 + quad * 8);
        acc1 = __builtin_amdgcn_mfma_f32_16x16x32_bf16(a1, whf[kb], acc1, 0, 0, 0);
        bf16x8 a2 = *(const bf16x8*)(hA0 + fr * 512 + (kb + 1) * 32 + quad * 8);
        acc2 = __builtin_amdgcn_mfma_f32_16x16x32_bf16(a2, wxf[kb + 1], acc2, 0, 0, 0);
        bf16x8 a3 = *(const bf16x8*)(hA1 + fr * 512 + (kb + 1) * 32 + quad * 8);
        acc3 = __builtin_amdgcn_mfma_f32_16x16x32_bf16(a3, whf[kb + 1], acc3, 0, 0, 0);
      }
      f32x4 acc = (acc0 + acc1) + (acc2 + acc3);
#pragma unroll
      for (int r = 0; r < 4; ++r) Cst[wave][quad * 4 + r][fr] = acc[r];
      int hv = 0; ushort4 p;
      if (gl) {
        float pi = Cst[wave][b][dl * 4 + 0] + bias4.x;
        float pf = Cst[wave][b][dl * 4 + 1] + bias4.y;
        float pg = Cst[wave][b][dl * 4 + 2] + bias4.z;
        float po = Cst[wave][b][dl * 4 + 3] + bias4.w;
        float ig = sigm(pi), fg = sigm(pf), gg = tanhr(pg), og = sigm(po);
        c_state = fg * c_state + ig * gg;
        hv = f2bf(og * tanhr(c_state));
        int g0 = __shfl(hv, b + 0), g1 = __shfl(hv, b + 8);
        int g2 = __shfl(hv, b + 16), g3 = __shfl(hv, b + 24);
        p = { (u16)g0, (u16)g1, (u16)g2, (u16)g3 };
        if (lane < 8)
          *(ushort4*)(H1ring + (t & 1) * 8192 + b * 512 + dbase) = p;
      }
      __syncthreads();
      if (tid == 0)
        __hip_atomic_store(&flags[wg * FS], t + 1, __ATOMIC_RELEASE, __HIP_MEMORY_SCOPE_AGENT);
      if (gl && lane < 8)   // off critical path: consumed by logits GEMM at kernel end
        *(ushort4*)(Hseq1 + (size_t)(b * T + t) * 512 + dbase) = p;
    }
  }
}

extern "C" void kernel_launch(void* const* d_in, const int* in_sizes, int n_in,
                              void* d_out, int out_size, void* d_ws, size_t ws_size,
                              hipStream_t stream) {
  (void)in_sizes; (void)n_in; (void)out_size; (void)ws_size;
  const int*   tokens = (const int*)d_in[0];
  const float* embed  = (const float*)d_in[1];
  const float* Wx0 = (const float*)d_in[2];
  const float* Wh0 = (const float*)d_in[3];
  const float* b0  = (const float*)d_in[4];
  const float* Wx1 = (const float*)d_in[5];
  const float* Wh1 = (const float*)d_in[6];
  const float* b1  = (const float*)d_in[7];
  const float* Wout = (const float*)d_in[8];
  const float* bout = (const float*)d_in[9];

  char* ws = (char*)d_ws;
  size_t off = 0;
  auto alloc = [&](size_t bytes) -> char* {
    char* p = ws + off; off += (bytes + 255) & ~(size_t)255; return p;
  };
  float* xw  = (float*)alloc((size_t)M4 * G * 4);  // 32 MB; WoutT aliases after scan
  u16* WoutT = (u16*)xw;
  u16* Xbf   = (u16*)alloc((size_t)M4 * D * 2);
  u16* WxT0  = (u16*)alloc((size_t)G * D * 2);
  u16* WhT0  = (u16*)alloc((size_t)G * D * 2);
  u16* WxT1  = (u16*)alloc((size_t)G * D * 2);
  u16* WhT1  = (u16*)alloc((size_t)G * D * 2);
  u16* Hseq1 = (u16*)alloc((size_t)M4 * D * 2);
  float* b0p = (float*)alloc(G * 4);
  float* b1p = (float*)alloc(G * 4);
  char* zbase = ws + off;                           // zero-init region
  u16* H0ring = (u16*)alloc(2 * 16 * 512 * 2);
  u16* H1ring = (u16*)alloc(2 * 16 * 512 * 2);
  int* flags  = (int*)alloc(64 * FS * 4);
  size_t zbytes = (size_t)((ws + off) - zbase);
  hipMemsetAsync(zbase, 0, zbytes, stream);

  embed_kernel<<<M4, 256, 0, stream>>>(tokens, embed, Xbf);
  transpose_cast<true ><<<dim3(G / 64, 8), 256, 0, stream>>>(Wx0, WxT0, G);
  transpose_cast<true ><<<dim3(G / 64, 8), 256, 0, stream>>>(Wh0, WhT0, G);
  transpose_cast<true ><<<dim3(G / 64, 8), 256, 0, stream>>>(Wx1, WxT1, G);
  transpose_cast<true ><<<dim3(G / 64, 8), 256, 0, stream>>>(Wh1, WhT1, G);
  bias_perm<<<G / 256, 256, 0, stream>>>(b0, b0p);
  bias_perm<<<G / 256, 256, 0, stream>>>(b1, b1p);

  gemm_bt<<<dim3(G / 128, M4 / 128), 256, 0, stream>>>(Xbf, WxT0, b0p, xw, G, D);
  lstm_fused<<<64, 256, 0, stream>>>(WhT0, WhT1, WxT1, xw, b1p, H0ring, H1ring, Hseq1, flags);
  transpose_cast<false><<<dim3(V / 64, 8), 256, 0, stream>>>(Wout, WoutT, V);
  gemm_bt<<<dim3(V / 128, M4 / 128), 256, 0, stream>>>(Hseq1, WoutT, bout, (float*)d_out, V, D);
}